// Round 1
// baseline (507.464 us; speedup 1.0000x reference)
//
#include <hip/hip_runtime.h>
#include <hip/hip_bf16.h>

#define NUM_NODES 262144
#define HIDDEN 256
#define NHID 128
#define NUM_GRAPHS 1024

typedef float f32x4 __attribute__((ext_vector_type(4)));
typedef short s16x8 __attribute__((ext_vector_type(8)));

// f32 -> bf16 bits with round-to-nearest-even
__device__ __forceinline__ short f2bf(float f) {
    unsigned u = __builtin_bit_cast(unsigned, f);
    unsigned r = (u + 0x7FFFu + ((u >> 16) & 1u)) >> 16;
    return (short)r;
}

__device__ __forceinline__ int lower_bound(const int* __restrict__ b, int n, int val) {
    int lo = 0, hi = n;
    while (lo < hi) {
        int mid = (lo + hi) >> 1;
        if (b[mid] < val) lo = mid + 1; else hi = mid;
    }
    return lo;
}

// ---------------------------------------------------------------------------
// Kernel 0: swizzle W1 (f32 [256][128]) into bf16 B-fragment order in ws.
// Entry e = (kt*8+nt)*64 + lane ; 8 contiguous bf16 = B[k=kt*32+quad*8+j][n=nt*16+(lane&15)]
// ---------------------------------------------------------------------------
__global__ __launch_bounds__(256) void prep_w1(const float* __restrict__ W1,
                                               short* __restrict__ w1swz) {
    int e = blockIdx.x * 256 + threadIdx.x;   // 0..4095
    int l  = e & 63;
    int nt = (e >> 6) & 7;
    int kt = e >> 9;
    int kbase = kt * 32 + ((l >> 4) << 3);
    int n = nt * 16 + (l & 15);
#pragma unroll
    for (int j = 0; j < 8; ++j)
        w1swz[e * 8 + j] = f2bf(W1[(size_t)(kbase + j) * NHID + n]);
}

// ---------------------------------------------------------------------------
// Kernel 1: scores s[n] = tanh(x[n]@W1 + b1) @ W2 + b2 via bf16 MFMA.
// Grid 512 blocks x 256 thr; block handles 512 nodes (8 groups x 4 waves x 16).
// ---------------------------------------------------------------------------
__global__ __launch_bounds__(256) void scores_kernel(
    const float* __restrict__ x, const short* __restrict__ w1swz,
    const float* __restrict__ b1, const float* __restrict__ W2,
    const float* __restrict__ b2, float* __restrict__ s) {
    __shared__ short w1s[32768];  // 64 KB, fragment-ordered bf16 W1

    int tid = threadIdx.x;
    // Stage swizzled W1 into LDS (coalesced 16B chunks)
    for (int i = tid; i < 4096; i += 256)
        ((f32x4*)w1s)[i] = ((const f32x4*)w1swz)[i];
    __syncthreads();

    int wave = tid >> 6, lane = tid & 63;
    int quad = lane >> 4, l15 = lane & 15;

    float b1v[8], w2v[8];
#pragma unroll
    for (int nt = 0; nt < 8; ++nt) {
        b1v[nt] = b1[nt * 16 + l15];
        w2v[nt] = W2[nt * 16 + l15];
    }
    float b2v = b2[0];

    for (int g = 0; g < 8; ++g) {
        int tile = blockIdx.x * 512 + g * 64 + wave * 16;
        f32x4 acc[8];
#pragma unroll
        for (int nt = 0; nt < 8; ++nt) acc[nt] = (f32x4){0.f, 0.f, 0.f, 0.f};

        const float* xrow = x + (size_t)(tile + l15) * HIDDEN + quad * 8;
#pragma unroll
        for (int kt = 0; kt < 8; ++kt) {
            const float* xp = xrow + kt * 32;
            f32x4 a0 = *(const f32x4*)xp;
            f32x4 a1 = *(const f32x4*)(xp + 4);
            s16x8 af;
            af[0] = f2bf(a0.x); af[1] = f2bf(a0.y);
            af[2] = f2bf(a0.z); af[3] = f2bf(a0.w);
            af[4] = f2bf(a1.x); af[5] = f2bf(a1.y);
            af[6] = f2bf(a1.z); af[7] = f2bf(a1.w);
#pragma unroll
            for (int nt = 0; nt < 8; ++nt) {
                s16x8 bf = *(const s16x8*)&w1s[((kt * 8 + nt) * 64 + lane) * 8];
                acc[nt] = __builtin_amdgcn_mfma_f32_16x16x32_bf16(af, bf, acc[nt], 0, 0, 0);
            }
        }

        // Epilogue: h = tanh(acc + b1); partial = h * W2[col]; reduce over cols
        float p[4] = {0.f, 0.f, 0.f, 0.f};
#pragma unroll
        for (int nt = 0; nt < 8; ++nt) {
#pragma unroll
            for (int r = 0; r < 4; ++r) {
                float h = tanhf(acc[nt][r] + b1v[nt]);
                p[r] += h * w2v[nt];
            }
        }
        // sum across the 16 lanes of each quad (cols 0..15 of this hidden slice)
#pragma unroll
        for (int r = 0; r < 4; ++r) {
#pragma unroll
            for (int off = 1; off < 16; off <<= 1)
                p[r] += __shfl_xor(p[r], off);
        }
        if (l15 == 0) {
            f32x4 sv;
            sv.x = p[0] + b2v; sv.y = p[1] + b2v;
            sv.z = p[2] + b2v; sv.w = p[3] + b2v;
            *(f32x4*)(s + tile + quad * 4) = sv;
        }
    }
}

// ---------------------------------------------------------------------------
// Kernel 2: segmented softmax weights. One block per graph (batch is sorted).
// ---------------------------------------------------------------------------
__global__ __launch_bounds__(256) void softmax_kernel(
    const int* __restrict__ batch, const float* __restrict__ s,
    float* __restrict__ w) {
    __shared__ float red[256];
    __shared__ int seg[2];
    int g = blockIdx.x, tid = threadIdx.x;
    if (tid == 0) {
        seg[0] = lower_bound(batch, NUM_NODES, g);
        seg[1] = lower_bound(batch, NUM_NODES, g + 1);
    }
    __syncthreads();
    int start = seg[0], end = seg[1];
    if (start >= end) return;  // uniform across block

    float m = -1e30f;
    for (int i = start + tid; i < end; i += 256) m = fmaxf(m, s[i]);
    red[tid] = m; __syncthreads();
    for (int o = 128; o > 0; o >>= 1) {
        if (tid < o) red[tid] = fmaxf(red[tid], red[tid + o]);
        __syncthreads();
    }
    float M = red[0]; __syncthreads();

    float sum = 0.f;
    for (int i = start + tid; i < end; i += 256) sum += __expf(s[i] - M);
    red[tid] = sum; __syncthreads();
    for (int o = 128; o > 0; o >>= 1) {
        if (tid < o) red[tid] += red[tid + o];
        __syncthreads();
    }
    float inv = 1.0f / (red[0] + 1e-8f);

    for (int i = start + tid; i < end; i += 256) w[i] = __expf(s[i] - M) * inv;
}

// ---------------------------------------------------------------------------
// Kernel 3: out[g][f] = sum_{n in seg(g)} x[n][f] * w[n]. Block per graph,
// thread per feature (coalesced 1 KB/iter); w[n] loads are block-uniform.
// ---------------------------------------------------------------------------
__global__ __launch_bounds__(256) void pool_kernel(
    const int* __restrict__ batch, const float* __restrict__ x,
    const float* __restrict__ w, float* __restrict__ out) {
    int g = blockIdx.x, f = threadIdx.x;
    int start = lower_bound(batch, NUM_NODES, g);
    int end   = lower_bound(batch, NUM_NODES, g + 1);
    float acc = 0.f;
    int n = start;
    for (; n + 4 <= end; n += 4) {
        float w0 = w[n], w1 = w[n + 1], w2 = w[n + 2], w3 = w[n + 3];
        acc += x[(size_t)n * HIDDEN + f] * w0;
        acc += x[(size_t)(n + 1) * HIDDEN + f] * w1;
        acc += x[(size_t)(n + 2) * HIDDEN + f] * w2;
        acc += x[(size_t)(n + 3) * HIDDEN + f] * w3;
    }
    for (; n < end; ++n) acc += x[(size_t)n * HIDDEN + f] * w[n];
    out[(size_t)g * HIDDEN + f] = acc;  // empty graphs write 0 (matches segment_sum)
}

extern "C" void kernel_launch(void* const* d_in, const int* in_sizes, int n_in,
                              void* d_out, int out_size, void* d_ws, size_t ws_size,
                              hipStream_t stream) {
    const float* x     = (const float*)d_in[0];
    const int*   batch = (const int*)d_in[1];
    const float* W1    = (const float*)d_in[2];
    const float* b1    = (const float*)d_in[3];
    const float* W2    = (const float*)d_in[4];
    const float* b2    = (const float*)d_in[5];
    float* out = (float*)d_out;

    char* ws = (char*)d_ws;
    float* s      = (float*)ws;                                   // 1 MB
    float* w      = (float*)(ws + (size_t)NUM_NODES * 4);         // 1 MB
    short* w1swz  = (short*)(ws + (size_t)NUM_NODES * 8);         // 64 KB

    hipLaunchKernelGGL(prep_w1, dim3(16), dim3(256), 0, stream, W1, w1swz);
    hipLaunchKernelGGL(scores_kernel, dim3(512), dim3(256), 0, stream,
                       x, w1swz, b1, W2, b2, s);
    hipLaunchKernelGGL(softmax_kernel, dim3(NUM_GRAPHS), dim3(256), 0, stream,
                       batch, s, w);
    hipLaunchKernelGGL(pool_kernel, dim3(NUM_GRAPHS), dim3(256), 0, stream,
                       batch, x, w, out);
}

// Round 2
// 465.722 us; speedup vs baseline: 1.0896x; 1.0896x over previous
//
#include <hip/hip_runtime.h>
#include <hip/hip_bf16.h>

#define NUM_NODES 262144
#define HIDDEN 256
#define NHID 128
#define NUM_GRAPHS 1024

typedef float f32x4 __attribute__((ext_vector_type(4)));
typedef short s16x8 __attribute__((ext_vector_type(8)));

// f32 -> bf16 bits with round-to-nearest-even
__device__ __forceinline__ short f2bf(float f) {
    unsigned u = __builtin_bit_cast(unsigned, f);
    unsigned r = (u + 0x7FFFu + ((u >> 16) & 1u)) >> 16;
    return (short)r;
}

// tanh via native exp: ~6 VALU ops vs ~20+ for libm tanhf.
// Large |v| saturates correctly (exp->inf => 1; exp->0 => -1).
__device__ __forceinline__ float fast_tanh(float v) {
    float e = __expf(2.0f * v);
    return 1.0f - __fdividef(2.0f, e + 1.0f);
}

__device__ __forceinline__ int lower_bound(const int* __restrict__ b, int n, int val) {
    int lo = 0, hi = n;
    while (lo < hi) {
        int mid = (lo + hi) >> 1;
        if (b[mid] < val) lo = mid + 1; else hi = mid;
    }
    return lo;
}

// ---------------------------------------------------------------------------
// Kernel 0: swizzle W1 (f32 [256][128]) into bf16 B-fragment order in ws.
// Entry e = (kt*8+nt)*64 + lane ; 8 contiguous bf16 = B[k=kt*32+quad*8+j][n=nt*16+(lane&15)]
// ---------------------------------------------------------------------------
__global__ __launch_bounds__(256) void prep_w1(const float* __restrict__ W1,
                                               short* __restrict__ w1swz) {
    int e = blockIdx.x * 256 + threadIdx.x;   // 0..4095
    int l  = e & 63;
    int nt = (e >> 6) & 7;
    int kt = e >> 9;
    int kbase = kt * 32 + ((l >> 4) << 3);
    int n = nt * 16 + (l & 15);
#pragma unroll
    for (int j = 0; j < 8; ++j)
        w1swz[e * 8 + j] = f2bf(W1[(size_t)(kbase + j) * NHID + n]);
}

// ---------------------------------------------------------------------------
// Kernel 1: scores s[n] = tanh(x[n]@W1 + b1) @ W2 + b2 via bf16 MFMA.
// Grid 512 blocks x 256 thr; block handles 512 nodes (8 groups x 4 waves x 16).
// All 16 global loads for a 16-row tile are issued back-to-back (16 KB in
// flight per wave) before the convert + 64-MFMA burst -> latency hidden.
// ---------------------------------------------------------------------------
__global__ __launch_bounds__(256) void scores_kernel(
    const float* __restrict__ x, const short* __restrict__ w1swz,
    const float* __restrict__ b1, const float* __restrict__ W2,
    const float* __restrict__ b2, float* __restrict__ s) {
    __shared__ short w1s[32768];  // 64 KB, fragment-ordered bf16 W1

    int tid = threadIdx.x;
    for (int i = tid; i < 4096; i += 256)
        ((f32x4*)w1s)[i] = ((const f32x4*)w1swz)[i];
    __syncthreads();

    int wave = tid >> 6, lane = tid & 63;
    int quad = lane >> 4, l15 = lane & 15;

    float b1v[8], w2v[8];
#pragma unroll
    for (int nt = 0; nt < 8; ++nt) {
        b1v[nt] = b1[nt * 16 + l15];
        w2v[nt] = W2[nt * 16 + l15];
    }
    float b2v = b2[0];

    for (int g = 0; g < 8; ++g) {
        int tile = blockIdx.x * 512 + g * 64 + wave * 16;
        const float* xrow = x + (size_t)(tile + l15) * HIDDEN + quad * 8;

        // 1) Batch-issue all 16 global dwordx4 loads for this tile
        f32x4 a[16];
#pragma unroll
        for (int kt = 0; kt < 8; ++kt) {
            a[2 * kt]     = *(const f32x4*)(xrow + kt * 32);
            a[2 * kt + 1] = *(const f32x4*)(xrow + kt * 32 + 4);
        }

        // 2) Convert f32 -> bf16 fragments
        s16x8 af[8];
#pragma unroll
        for (int kt = 0; kt < 8; ++kt) {
            f32x4 a0 = a[2 * kt], a1 = a[2 * kt + 1];
            af[kt][0] = f2bf(a0.x); af[kt][1] = f2bf(a0.y);
            af[kt][2] = f2bf(a0.z); af[kt][3] = f2bf(a0.w);
            af[kt][4] = f2bf(a1.x); af[kt][5] = f2bf(a1.y);
            af[kt][6] = f2bf(a1.z); af[kt][7] = f2bf(a1.w);
        }

        // 3) MFMA burst (B-frags from LDS)
        f32x4 acc[8];
#pragma unroll
        for (int nt = 0; nt < 8; ++nt) acc[nt] = (f32x4){0.f, 0.f, 0.f, 0.f};
#pragma unroll
        for (int kt = 0; kt < 8; ++kt) {
#pragma unroll
            for (int nt = 0; nt < 8; ++nt) {
                s16x8 bf = *(const s16x8*)&w1s[((kt * 8 + nt) * 64 + lane) * 8];
                acc[nt] = __builtin_amdgcn_mfma_f32_16x16x32_bf16(af[kt], bf, acc[nt], 0, 0, 0);
            }
        }

        // 4) Epilogue: h = tanh(acc + b1); p = h * W2[col]; reduce over 16 cols
        float p[4] = {0.f, 0.f, 0.f, 0.f};
#pragma unroll
        for (int nt = 0; nt < 8; ++nt) {
#pragma unroll
            for (int r = 0; r < 4; ++r) {
                float h = fast_tanh(acc[nt][r] + b1v[nt]);
                p[r] += h * w2v[nt];
            }
        }
#pragma unroll
        for (int r = 0; r < 4; ++r) {
#pragma unroll
            for (int off = 1; off < 16; off <<= 1)
                p[r] += __shfl_xor(p[r], off);
        }
        if (l15 == 0) {
            f32x4 sv;
            sv.x = p[0] + b2v; sv.y = p[1] + b2v;
            sv.z = p[2] + b2v; sv.w = p[3] + b2v;
            *(f32x4*)(s + tile + quad * 4) = sv;
        }
    }
}

// ---------------------------------------------------------------------------
// Kernel 2: segmented softmax weights. One block per graph (batch is sorted).
// ---------------------------------------------------------------------------
__global__ __launch_bounds__(256) void softmax_kernel(
    const int* __restrict__ batch, const float* __restrict__ s,
    float* __restrict__ w) {
    __shared__ float red[256];
    __shared__ int seg[2];
    int g = blockIdx.x, tid = threadIdx.x;
    if (tid == 0) {
        seg[0] = lower_bound(batch, NUM_NODES, g);
        seg[1] = lower_bound(batch, NUM_NODES, g + 1);
    }
    __syncthreads();
    int start = seg[0], end = seg[1];
    if (start >= end) return;  // uniform across block

    float m = -1e30f;
    for (int i = start + tid; i < end; i += 256) m = fmaxf(m, s[i]);
    red[tid] = m; __syncthreads();
    for (int o = 128; o > 0; o >>= 1) {
        if (tid < o) red[tid] = fmaxf(red[tid], red[tid + o]);
        __syncthreads();
    }
    float M = red[0]; __syncthreads();

    float sum = 0.f;
    for (int i = start + tid; i < end; i += 256) sum += __expf(s[i] - M);
    red[tid] = sum; __syncthreads();
    for (int o = 128; o > 0; o >>= 1) {
        if (tid < o) red[tid] += red[tid + o];
        __syncthreads();
    }
    float inv = 1.0f / (red[0] + 1e-8f);

    for (int i = start + tid; i < end; i += 256) w[i] = __expf(s[i] - M) * inv;
}

// ---------------------------------------------------------------------------
// Kernel 3: chunked weighted pool with atomic flush. 8192 blocks x 32 nodes;
// thread = feature. All 32 x-values prefetched into registers (8 KB in
// flight per wave); local accumulate, atomicAdd once per distinct graph in
// the chunk (~1.1 per block). Requires out pre-zeroed.
// ---------------------------------------------------------------------------
#define CHUNK 32
__global__ __launch_bounds__(256) void pool_atomic(
    const int* __restrict__ batch, const float* __restrict__ x,
    const float* __restrict__ w, float* __restrict__ out) {
    int n0 = blockIdx.x * CHUNK;
    int f = threadIdx.x;

    float xv[CHUNK];
#pragma unroll
    for (int i = 0; i < CHUNK; ++i)
        xv[i] = x[(size_t)(n0 + i) * HIDDEN + f];

    float acc = 0.f;
    int cur = batch[n0];
#pragma unroll
    for (int i = 0; i < CHUNK; ++i) {
        int b = batch[n0 + i];
        float wv = w[n0 + i];
        if (b != cur) {                       // block-uniform branch
            atomicAdd(&out[(size_t)cur * HIDDEN + f], acc);
            acc = 0.f;
            cur = b;
        }
        acc += xv[i] * wv;
    }
    atomicAdd(&out[(size_t)cur * HIDDEN + f], acc);
}

extern "C" void kernel_launch(void* const* d_in, const int* in_sizes, int n_in,
                              void* d_out, int out_size, void* d_ws, size_t ws_size,
                              hipStream_t stream) {
    const float* x     = (const float*)d_in[0];
    const int*   batch = (const int*)d_in[1];
    const float* W1    = (const float*)d_in[2];
    const float* b1    = (const float*)d_in[3];
    const float* W2    = (const float*)d_in[4];
    const float* b2    = (const float*)d_in[5];
    float* out = (float*)d_out;

    char* ws = (char*)d_ws;
    float* s      = (float*)ws;                                   // 1 MB
    float* w      = (float*)(ws + (size_t)NUM_NODES * 4);         // 1 MB
    short* w1swz  = (short*)(ws + (size_t)NUM_NODES * 8);         // 64 KB

    hipLaunchKernelGGL(prep_w1, dim3(16), dim3(256), 0, stream, W1, w1swz);
    hipLaunchKernelGGL(scores_kernel, dim3(512), dim3(256), 0, stream,
                       x, w1swz, b1, W2, b2, s);
    hipLaunchKernelGGL(softmax_kernel, dim3(NUM_GRAPHS), dim3(256), 0, stream,
                       batch, s, w);
    hipMemsetAsync(d_out, 0, (size_t)out_size * sizeof(float), stream);
    hipLaunchKernelGGL(pool_atomic, dim3(NUM_NODES / CHUNK), dim3(256), 0, stream,
                       batch, x, w, out);
}